// Round 14
// baseline (667.699 us; speedup 1.0000x reference)
//
#include <hip/hip_runtime.h>
#include <hip/hip_bf16.h>

typedef __bf16 bf16_t;
typedef bf16_t bf16x8 __attribute__((ext_vector_type(8)));
typedef float f32x4 __attribute__((ext_vector_type(4)));
typedef unsigned short ushort_t;

#define LD 104   // padded LDS row stride (bf16 elems) for GEMM staging tiles

__device__ __forceinline__ float bf2f(unsigned short u) {
    return __uint_as_float(((unsigned)u) << 16);
}
__device__ __forceinline__ unsigned short f2bfu(float x) {
    union { bf16_t b; unsigned short u; } c; c.b = (bf16_t)x; return c.u;
}
__device__ __forceinline__ unsigned pk2(float x, float y) {
    return (unsigned)f2bfu(x) | ((unsigned)f2bfu(y) << 16);
}

#define LD6(PTR, OUT) { \
    unsigned u0 = *(const unsigned*)(PTR); \
    unsigned u1 = *(const unsigned*)((PTR) + 2); \
    unsigned u2 = *(const unsigned*)((PTR) + 4); \
    OUT[0] = bf2f(u0 & 0xffff); OUT[1] = bf2f(u0 >> 16); \
    OUT[2] = bf2f(u1 & 0xffff); OUT[3] = bf2f(u1 >> 16); \
    OUT[4] = bf2f(u2 & 0xffff); OUT[5] = bf2f(u2 >> 16); }

// load 12 consecutive bf16 (6 dwords) -> two 6-float arrays
#define LD12(PTR, O1, O2) { \
    const unsigned* _p = (const unsigned*)(PTR); \
    unsigned u0 = _p[0], u1 = _p[1], u2 = _p[2], u3 = _p[3], u4 = _p[4], u5 = _p[5]; \
    O1[0] = bf2f(u0 & 0xffff); O1[1] = bf2f(u0 >> 16); \
    O1[2] = bf2f(u1 & 0xffff); O1[3] = bf2f(u1 >> 16); \
    O1[4] = bf2f(u2 & 0xffff); O1[5] = bf2f(u2 >> 16); \
    O2[0] = bf2f(u3 & 0xffff); O2[1] = bf2f(u3 >> 16); \
    O2[2] = bf2f(u4 & 0xffff); O2[3] = bf2f(u4 >> 16); \
    O2[4] = bf2f(u5 & 0xffff); O2[5] = bf2f(u5 >> 16); }

// ---------------- pack all 5 weights into per-lane MFMA B-fragment order ----------------
__global__ void pack_all_kernel(const float* __restrict__ A, const float* __restrict__ B,
                                const float* __restrict__ C, const float* __restrict__ Dw,
                                const float* __restrict__ Ew, bf16_t* __restrict__ wpA) {
    int idx = blockIdx.x * 256 + threadIdx.x;
    if (idx >= 5 * 1152) return;
    int m = idx / 1152, r = idx % 1152;
    int frag = r >> 6, l = r & 63;
    int tn = frag / 3, kk = frag % 3;
    const float* W = (m == 0) ? A : (m == 1) ? B : (m == 2) ? C : (m == 3) ? Dw : Ew;
    int row = (l & 15) * 6 + tn;
    int c0 = kk * 32 + (l >> 4) * 8;
    bf16_t* o = wpA + (size_t)idx * 8;
#pragma unroll
    for (int j = 0; j < 8; ++j) o[j] = (bf16_t)W[row * 96 + c0 + j];
}

// ---------------- node GEMM (all 4 mats, h staged once) ----------------
// gpack[n][288]: [lr*12..+5]=Bh, [lr*12+6..+11]=Dh, [192+lr*6..]=El(+Cb)
__global__ __launch_bounds__(256) void node_gemm_all_kernel(
    const float* __restrict__ h, const bf16_t* __restrict__ wpA,
    const float* __restrict__ Ab, const float* __restrict__ Bb,
    const float* __restrict__ Db, const float* __restrict__ Eb,
    const float* __restrict__ Cb,
    float* __restrict__ nodeF_A, ushort_t* __restrict__ gpack, int N)
{
    __shared__ __align__(16) bf16_t sx[64 * LD];
    const int n0 = blockIdx.x * 64;
    const int t = threadIdx.x;
    for (int i = t; i < 64 * 24; i += 256) {
        int r = i / 24, c4 = i % 24;
        int n = n0 + r;
        float4 v = (n < N) ? ((const float4*)h)[(size_t)n * 24 + c4]
                           : make_float4(0.f, 0.f, 0.f, 0.f);
        bf16_t* p = &sx[r * LD + c4 * 4];
        p[0] = (bf16_t)v.x; p[1] = (bf16_t)v.y; p[2] = (bf16_t)v.z; p[3] = (bf16_t)v.w;
    }
    __syncthreads();

    const int w = t >> 6, l = t & 63;
    const int lr = l & 15, lkb = (l >> 4) * 8;
    bf16x8 a[3];
    const bf16_t* aP = &sx[(w * 16 + lr) * LD + lkb];
#pragma unroll
    for (int kk = 0; kk < 3; ++kk) a[kk] = *(const bf16x8*)(aP + kk * 32);
    const int rowb = (l >> 4) * 4;

#pragma unroll
    for (int mat = 0; mat < 4; ++mat) {
        const int widx = (mat < 2) ? mat : mat + 1;
        const float* bias = (mat == 0) ? Ab : (mat == 1) ? Bb : (mat == 2) ? Db : Eb;
        f32x4 acc[6];
#pragma unroll
        for (int i = 0; i < 6; ++i) acc[i] = (f32x4){0.f, 0.f, 0.f, 0.f};
        const bf16x8* wp = (const bf16x8*)(wpA + (size_t)widx * 9216);
#pragma unroll
        for (int kk = 0; kk < 3; ++kk) {
#pragma unroll
            for (int tn = 0; tn < 6; ++tn) {
                bf16x8 b = wp[(tn * 3 + kk) * 64 + l];
                acc[tn] = __builtin_amdgcn_mfma_f32_16x16x32_bf16(a[kk], b, acc[tn], 0, 0, 0);
            }
        }
        float b6[6];
        {
            float2 b0 = *(const float2*)(bias + lr * 6);
            float2 b1 = *(const float2*)(bias + lr * 6 + 2);
            float2 b2 = *(const float2*)(bias + lr * 6 + 4);
            b6[0] = b0.x; b6[1] = b0.y; b6[2] = b1.x; b6[3] = b1.y; b6[4] = b2.x; b6[5] = b2.y;
        }
        if (mat == 3) {
            float2 c0 = *(const float2*)(Cb + lr * 6);
            float2 c1 = *(const float2*)(Cb + lr * 6 + 2);
            float2 c2 = *(const float2*)(Cb + lr * 6 + 4);
            b6[0] += c0.x; b6[1] += c0.y; b6[2] += c1.x; b6[3] += c1.y; b6[4] += c2.x; b6[5] += c2.y;
        }
#pragma unroll
        for (int i = 0; i < 4; ++i) {
            int n = n0 + w * 16 + rowb + i;
            if (n < N) {
                float v0 = acc[0][i] + b6[0], v1 = acc[1][i] + b6[1];
                float v2 = acc[2][i] + b6[2], v3 = acc[3][i] + b6[3];
                float v4 = acc[4][i] + b6[4], v5 = acc[5][i] + b6[5];
                if (mat == 0) {
                    float* p = nodeF_A + (size_t)n * 96 + lr * 6;
                    *(float2*)p = make_float2(v0, v1);
                    *(float2*)(p + 2) = make_float2(v2, v3);
                    *(float2*)(p + 4) = make_float2(v4, v5);
                } else {
                    size_t off = (mat == 1) ? ((size_t)n * 288 + lr * 12)
                               : (mat == 2) ? ((size_t)n * 288 + lr * 12 + 6)
                                            : ((size_t)n * 288 + 192 + lr * 6);
                    unsigned* op = (unsigned*)(gpack + off);
                    op[0] = pk2(v0, v1); op[1] = pk2(v2, v3); op[2] = pk2(v4, v5);
                }
            }
        }
    }
}

// ---------------- Ce GEMM: en_s[inv[row]][96] = bf16(e[row] @ Cw^T) ----------------
__global__ __launch_bounds__(256) void ce_gemm_kernel(
    const float* __restrict__ eP, const bf16_t* __restrict__ wpackC,
    const int* __restrict__ inv, ushort_t* __restrict__ en_s, int E)
{
    __shared__ __align__(16) bf16_t sx[64 * LD];
    const int n0 = blockIdx.x * 64;
    const int t = threadIdx.x;
    for (int i = t; i < 64 * 24; i += 256) {
        int r = i / 24, c4 = i % 24;
        int n = n0 + r;
        float4 v = (n < E) ? ((const float4*)eP)[(size_t)n * 24 + c4]
                           : make_float4(0.f, 0.f, 0.f, 0.f);
        bf16_t* p = &sx[r * LD + c4 * 4];
        p[0] = (bf16_t)v.x; p[1] = (bf16_t)v.y; p[2] = (bf16_t)v.z; p[3] = (bf16_t)v.w;
    }
    __syncthreads();

    const int w = t >> 6, l = t & 63;
    const int lr = l & 15, lkb = (l >> 4) * 8;
    f32x4 acc[6];
#pragma unroll
    for (int i = 0; i < 6; ++i) acc[i] = (f32x4){0.f, 0.f, 0.f, 0.f};
    const bf16_t* aP = &sx[(w * 16 + lr) * LD + lkb];
    const bf16x8* wp = (const bf16x8*)wpackC;
#pragma unroll
    for (int kk = 0; kk < 3; ++kk) {
        bf16x8 a = *(const bf16x8*)(aP + kk * 32);
#pragma unroll
        for (int tn = 0; tn < 6; ++tn) {
            bf16x8 b = wp[(tn * 3 + kk) * 64 + l];
            acc[tn] = __builtin_amdgcn_mfma_f32_16x16x32_bf16(a, b, acc[tn], 0, 0, 0);
        }
    }
    const int rowb = (l >> 4) * 4;
#pragma unroll
    for (int i = 0; i < 4; ++i) {
        int n = n0 + w * 16 + rowb + i;
        if (n < E) {
            int g = inv[n];
            unsigned* op = (unsigned*)(en_s + (size_t)g * 96 + lr * 6);
            op[0] = pk2(acc[0][i], acc[1][i]);
            op[1] = pk2(acc[2][i], acc[3][i]);
            op[2] = pk2(acc[4][i], acc[5][i]);
        }
    }
}

// ---------------- counting sort by dst ----------------
__global__ void hist_kernel(const int* __restrict__ dst, int* __restrict__ cnt, int E) {
    int i = blockIdx.x * 256 + threadIdx.x;
    if (i < E) atomicAdd(&cnt[dst[i]], 1);
}

// parallel unordered-base scan
__global__ __launch_bounds__(1024) void scan_assign_kernel(
    const int* __restrict__ cnt, int* __restrict__ startA, int* __restrict__ cursor,
    int* __restrict__ gtot, int N)
{
    __shared__ int wsum[16];
    __shared__ int sbase;
    const int t = threadIdx.x, w = t >> 6, l = t & 63;
    const int base = blockIdx.x * 1024;
    int v = (base + t < N) ? cnt[base + t] : 0;
    int x = v;
#pragma unroll
    for (int d = 1; d < 64; d <<= 1) {
        int y = __shfl_up(x, d, 64);
        if (l >= d) x += y;
    }
    if (l == 63) wsum[w] = x;
    __syncthreads();
    if (t == 0) {
        int run = 0;
#pragma unroll
        for (int i = 0; i < 16; ++i) { int tmp = wsum[i]; wsum[i] = run; run += tmp; }
        sbase = atomicAdd(gtot, run);
    }
    __syncthreads();
    int excl = sbase + wsum[w] + (x - v);
    if (base + t < N) { startA[base + t] = excl; cursor[base + t] = excl; }
}

// writes inv (orig->slot) and slot-order srcs; cursor ends at startA+cnt
__global__ void scatter_kernel(const int* __restrict__ dst, const int* __restrict__ src,
                               int* __restrict__ cursor, int* __restrict__ inv,
                               int* __restrict__ srcs, int E) {
    int i = blockIdx.x * 256 + threadIdx.x;
    if (i < E) {
        int d = dst[i];
        int p = atomicAdd(&cursor[d], 1);
        inv[i] = p;
        srcs[p] = src[i];
    }
}

// ---------------- CSR node-parallel aggregation, 2 groups per node ----------------
// Groups 2j/2j+1 (lanes +-16 in a wave) split node j's edge range; ash/asg fold
// via shfl_xor(16). Lane owns cols lr*6..lr*6+5. en_s: Ce in, e_new out in place.
__global__ __launch_bounds__(256, 8) void csr_agg_kernel(
    const int* __restrict__ startA, const int* __restrict__ rowend,
    const int* __restrict__ srcs,
    const ushort_t* __restrict__ gpack, ushort_t* __restrict__ en_s,
    const float* __restrict__ nodeF_A, float* __restrict__ h_new,
    float* __restrict__ stats, int N)
{
    __shared__ float bns[96], bnq[96], bsh[96], bqh[96];
    __shared__ int scnt;
    const int t = threadIdx.x;
    if (t == 0) scnt = 0;
    if (t < 96) { bns[t] = 0.f; bnq[t] = 0.f; bsh[t] = 0.f; bqh[t] = 0.f; }
    __syncthreads();

    const int gi = t >> 4, lr = t & 15, l = t & 63;
    const int half = gi & 1;
    const int n = blockIdx.x * 8 + (gi >> 1);
    float ls[6] = {0, 0, 0, 0, 0, 0}, lq[6] = {0, 0, 0, 0, 0, 0};
    float ash[6] = {0, 0, 0, 0, 0, 0}, asg[6] = {0, 0, 0, 0, 0, 0};
    const bool valid = (n < N);

    if (valid) {
        const int beg = startA[n];
        const int end = rowend[n];
        const int h0 = (end - beg + 1) >> 1;
        const int gs = half ? (beg + h0) : beg;
        const int ge = half ? end : (beg + h0);
        float eh6[6];
        LD6(gpack + (size_t)n * 288 + 192 + lr * 6, eh6);
        for (int g = gs; g < ge; ++g) {
            int s0 = srcs[g];
            float ce6[6], bh6[6], dh6[6], en6[6];
            LD6(en_s + (size_t)g * 96 + lr * 6, ce6);
            LD12(gpack + (size_t)s0 * 288 + lr * 12, bh6, dh6);
#pragma unroll
            for (int k = 0; k < 6; ++k) {
                float en = ce6[k] + dh6[k] + eh6[k];
                float sg = 1.f / (1.f + __expf(-en));
                ash[k] += sg * bh6[k]; asg[k] += sg;
                ls[k] += en; lq[k] += en * en;
                en6[k] = en;
            }
            unsigned* op = (unsigned*)(en_s + (size_t)g * 96 + lr * 6);
            op[0] = pk2(en6[0], en6[1]); op[1] = pk2(en6[2], en6[3]); op[2] = pk2(en6[4], en6[5]);
        }
    }
    // fold the two halves of each node (lanes +-16 within the wave)
#pragma unroll
    for (int k = 0; k < 6; ++k) {
        ash[k] += __shfl_xor(ash[k], 16, 64);
        asg[k] += __shfl_xor(asg[k], 16, 64);
    }
    if (valid && half == 0) {
        const float* ap = nodeF_A + (size_t)n * 96 + lr * 6;
        float* hp = h_new + (size_t)n * 96 + lr * 6;
#pragma unroll
        for (int k = 0; k < 6; ++k) {
            float v = ap[k] + ash[k] / (asg[k] + 1e-6f);
            hp[k] = v;
            atomicAdd(&bsh[lr * 6 + k], v);
            atomicAdd(&bqh[lr * 6 + k], v * v);
        }
    }
#pragma unroll
    for (int k = 0; k < 6; ++k) {
        float s = ls[k], q = lq[k];
        s += __shfl_xor(s, 16, 64); q += __shfl_xor(q, 16, 64);
        s += __shfl_xor(s, 32, 64); q += __shfl_xor(q, 32, 64);
        if (l < 16) {
            atomicAdd(&bns[lr * 6 + k], s);
            atomicAdd(&bnq[lr * 6 + k], q);
        }
    }
    __threadfence_block();
    int old = 0;
    if (l == 0) old = atomicAdd(&scnt, 1);
    old = __shfl(old, 0, 64);
    if (old == 3) {
        for (int j = l; j < 96; j += 64) {
            unsafeAtomicAdd(&stats[j], bsh[j]);
            unsafeAtomicAdd(&stats[96 + j], bqh[j]);
            unsafeAtomicAdd(&stats[192 + j], bns[j]);
            unsafeAtomicAdd(&stats[288 + j], bnq[j]);
        }
    }
}

// ---------------- edge output: natural order, gather e_new via inv ----------------
__global__ __launch_bounds__(256) void edge_out_b_kernel(
    const float* __restrict__ eP, const ushort_t* __restrict__ en_s,
    const int* __restrict__ inv, const float* __restrict__ coef,
    float* __restrict__ eout, long long total4)
{
    long long idx = (long long)blockIdx.x * 256 + threadIdx.x;
    if (idx >= total4) return;
    int row = (int)(idx / 24);
    int c4 = (int)(idx % 24) * 4;
    float4 res = ((const float4*)eP)[idx];
    int g = inv[row];
    ushort4 nb = *(const ushort4*)(en_s + (size_t)g * 96 + c4);
    float4 o;
    o.x = res.x + fmaxf(0.f, bf2f(nb.x) * coef[192 + c4 + 0] + coef[288 + c4 + 0]);
    o.y = res.y + fmaxf(0.f, bf2f(nb.y) * coef[192 + c4 + 1] + coef[288 + c4 + 1]);
    o.z = res.z + fmaxf(0.f, bf2f(nb.z) * coef[192 + c4 + 2] + coef[288 + c4 + 2]);
    o.w = res.w + fmaxf(0.f, bf2f(nb.w) * coef[192 + c4 + 3] + coef[288 + c4 + 3]);
    ((float4*)eout)[idx] = o;
}

// ---------------- stats -> scale/shift coefs ----------------
__global__ void finalize_stats_kernel(const float* __restrict__ stats, float* __restrict__ coef,
                                      const float* __restrict__ gh, const float* __restrict__ bh,
                                      const float* __restrict__ ge, const float* __restrict__ be,
                                      int N, int E)
{
    int t = threadIdx.x;
    if (t < 96) {
        float m = stats[t] / (float)N;
        float v = stats[96 + t] / (float)N - m * m;
        float rs = rsqrtf(v + 1e-5f);
        float sc = gh[t] * rs;
        coef[t] = sc;
        coef[96 + t] = bh[t] - m * sc;
    } else if (t < 192) {
        int c = t - 96;
        float m = stats[192 + c] / (float)E;
        float v = stats[288 + c] / (float)E - m * m;
        float rs = rsqrtf(v + 1e-5f);
        float sc = ge[c] * rs;
        coef[192 + c] = sc;
        coef[288 + c] = be[c] - m * sc;
    }
}

// ---------------- h output ----------------
__global__ __launch_bounds__(256) void h_out_kernel(
    const float* __restrict__ h, const float* __restrict__ h_new,
    const float* __restrict__ coef, float* __restrict__ out, int N)
{
    int idx = blockIdx.x * 256 + threadIdx.x;
    int total = N * 24;
    if (idx >= total) return;
    int c4 = (idx % 24) * 4;
    float4 hv = ((const float4*)h)[idx];
    float4 nv = ((const float4*)h_new)[idx];
    float4 o;
    o.x = hv.x + fmaxf(0.f, nv.x * coef[c4 + 0] + coef[96 + c4 + 0]);
    o.y = hv.y + fmaxf(0.f, nv.y * coef[c4 + 1] + coef[96 + c4 + 1]);
    o.z = hv.z + fmaxf(0.f, nv.z * coef[c4 + 2] + coef[96 + c4 + 2]);
    o.w = hv.w + fmaxf(0.f, nv.w * coef[c4 + 3] + coef[96 + c4 + 3]);
    ((float4*)out)[idx] = o;
}

extern "C" void kernel_launch(void* const* d_in, const int* in_sizes, int n_in,
                              void* d_out, int out_size, void* d_ws, size_t ws_size,
                              hipStream_t stream)
{
    const float* h   = (const float*)d_in[0];
    const float* e   = (const float*)d_in[1];
    const int*   src = (const int*)d_in[2];
    const int*   dst = (const int*)d_in[3];
    const float* Aw  = (const float*)d_in[4];
    const float* Ab  = (const float*)d_in[5];
    const float* Bw  = (const float*)d_in[6];
    const float* Bb  = (const float*)d_in[7];
    const float* Cw  = (const float*)d_in[8];
    const float* Cb  = (const float*)d_in[9];
    const float* Dw  = (const float*)d_in[10];
    const float* Db  = (const float*)d_in[11];
    const float* Ewt = (const float*)d_in[12];
    const float* Eb  = (const float*)d_in[13];
    const float* gh  = (const float*)d_in[14];
    const float* bh  = (const float*)d_in[15];
    const float* ge  = (const float*)d_in[16];
    const float* be  = (const float*)d_in[17];

    const int N = in_sizes[0] / 96;
    const int E = in_sizes[2];

    float* ws        = (float*)d_ws;
    float* nodeF_A   = ws;                               // N*96 f32
    float* h_new     = nodeF_A + (size_t)N * 96;         // N*96 f32
    float* stats     = h_new + (size_t)N * 96;           // 384
    float* coef      = stats + 384;                      // 384
    bf16_t* wpA      = (bf16_t*)(coef + 384);            // 5*9216 bf16
    int* cnt         = (int*)(wpA + 5 * 9216);           // N
    int* startA      = cnt + N;                          // N
    int* cursor      = startA + N;                       // N
    int* srcs        = cursor + N;                       // E
    int* inv         = srcs + E;                         // E
    ushort_t* gpack  = (ushort_t*)(inv + E);             // N*288
    ushort_t* en_s   = gpack + (size_t)N * 288;          // E*96
    int* gtot        = (int*)(en_s + (size_t)E * 96);    // 1

    const int nblk64 = (E + 63) / 64;
    const int nscan = (N + 1023) / 1024;

    hipMemsetAsync(cnt, 0, (size_t)N * sizeof(int), stream);
    hipMemsetAsync(gtot, 0, sizeof(int), stream);
    hipMemsetAsync(stats, 0, 384 * sizeof(float), stream);

    pack_all_kernel<<<dim3(23), dim3(256), 0, stream>>>(Aw, Bw, Cw, Dw, Ewt, wpA);
    node_gemm_all_kernel<<<dim3((N + 63) / 64), dim3(256), 0, stream>>>(
        h, wpA, Ab, Bb, Db, Eb, Cb, nodeF_A, gpack, N);
    hist_kernel<<<dim3((E + 255) / 256), dim3(256), 0, stream>>>(dst, cnt, E);
    scan_assign_kernel<<<dim3(nscan), dim3(1024), 0, stream>>>(cnt, startA, cursor, gtot, N);
    scatter_kernel<<<dim3((E + 255) / 256), dim3(256), 0, stream>>>(
        dst, src, cursor, inv, srcs, E);
    ce_gemm_kernel<<<dim3(nblk64), dim3(256), 0, stream>>>(
        e, wpA + 2 * 9216, inv, en_s, E);

    // cursor now holds row ends (startA + cnt); 2 groups per node -> 8 nodes/block
    csr_agg_kernel<<<dim3((N + 7) / 8), dim3(256), 0, stream>>>(
        startA, cursor, srcs, gpack, en_s, nodeF_A, h_new, stats, N);

    finalize_stats_kernel<<<dim3(1), dim3(192), 0, stream>>>(stats, coef, gh, bh, ge, be, N, E);
    h_out_kernel<<<dim3((N * 24 + 255) / 256), dim3(256), 0, stream>>>(
        h, h_new, coef, (float*)d_out, N);

    long long total4 = (long long)E * 24;
    edge_out_b_kernel<<<dim3((unsigned)((total4 + 255) / 256)), dim3(256), 0, stream>>>(
        e, en_s, inv, coef, (float*)d_out + (size_t)N * 96, total4);
}

// Round 15
// 592.881 us; speedup vs baseline: 1.1262x; 1.1262x over previous
//
#include <hip/hip_runtime.h>
#include <hip/hip_bf16.h>

typedef __bf16 bf16_t;
typedef bf16_t bf16x8 __attribute__((ext_vector_type(8)));
typedef float f32x4 __attribute__((ext_vector_type(4)));
typedef unsigned short ushort_t;

#define LD 104   // padded LDS row stride (bf16 elems) for GEMM staging tiles

__device__ __forceinline__ float bf2f(unsigned short u) {
    return __uint_as_float(((unsigned)u) << 16);
}
__device__ __forceinline__ unsigned short f2bfu(float x) {
    union { bf16_t b; unsigned short u; } c; c.b = (bf16_t)x; return c.u;
}
__device__ __forceinline__ unsigned pk2(float x, float y) {
    return (unsigned)f2bfu(x) | ((unsigned)f2bfu(y) << 16);
}

#define LD6(PTR, OUT) { \
    unsigned u0 = *(const unsigned*)(PTR); \
    unsigned u1 = *(const unsigned*)((PTR) + 2); \
    unsigned u2 = *(const unsigned*)((PTR) + 4); \
    OUT[0] = bf2f(u0 & 0xffff); OUT[1] = bf2f(u0 >> 16); \
    OUT[2] = bf2f(u1 & 0xffff); OUT[3] = bf2f(u1 >> 16); \
    OUT[4] = bf2f(u2 & 0xffff); OUT[5] = bf2f(u2 >> 16); }

// load 12 consecutive bf16 (6 dwords) -> two 6-float arrays
#define LD12(PTR, O1, O2) { \
    const unsigned* _p = (const unsigned*)(PTR); \
    unsigned u0 = _p[0], u1 = _p[1], u2 = _p[2], u3 = _p[3], u4 = _p[4], u5 = _p[5]; \
    O1[0] = bf2f(u0 & 0xffff); O1[1] = bf2f(u0 >> 16); \
    O1[2] = bf2f(u1 & 0xffff); O1[3] = bf2f(u1 >> 16); \
    O1[4] = bf2f(u2 & 0xffff); O1[5] = bf2f(u2 >> 16); \
    O2[0] = bf2f(u3 & 0xffff); O2[1] = bf2f(u3 >> 16); \
    O2[2] = bf2f(u4 & 0xffff); O2[3] = bf2f(u4 >> 16); \
    O2[4] = bf2f(u5 & 0xffff); O2[5] = bf2f(u5 >> 16); }

// ---------------- pack all 5 weights into per-lane MFMA B-fragment order ----------------
// fragment row for lane l, tile tn: physical col (l&15)*6 + tn
__global__ void pack_all_kernel(const float* __restrict__ A, const float* __restrict__ B,
                                const float* __restrict__ C, const float* __restrict__ Dw,
                                const float* __restrict__ Ew, bf16_t* __restrict__ wpA) {
    int idx = blockIdx.x * 256 + threadIdx.x;
    if (idx >= 5 * 1152) return;
    int m = idx / 1152, r = idx % 1152;
    int frag = r >> 6, l = r & 63;
    int tn = frag / 3, kk = frag % 3;
    const float* W = (m == 0) ? A : (m == 1) ? B : (m == 2) ? C : (m == 3) ? Dw : Ew;
    int row = (l & 15) * 6 + tn;
    int c0 = kk * 32 + (l >> 4) * 8;
    bf16_t* o = wpA + (size_t)idx * 8;
#pragma unroll
    for (int j = 0; j < 8; ++j) o[j] = (bf16_t)W[row * 96 + c0 + j];
}

// ---------------- node GEMM (all 4 mats, h staged once) ----------------
// mat 0 -> Ah f32 nodeF_A[n][96]
// gpack[n][288] layout (per lane lr): [lr*12 .. +5] = Bh cols lr*6..lr*6+5,
// [lr*12+6 .. +11] = Dh cols lr*6..; [192 + lr*6 ..] = El(+Cb) cols lr*6..
__global__ __launch_bounds__(256) void node_gemm_all_kernel(
    const float* __restrict__ h, const bf16_t* __restrict__ wpA,
    const float* __restrict__ Ab, const float* __restrict__ Bb,
    const float* __restrict__ Db, const float* __restrict__ Eb,
    const float* __restrict__ Cb,
    float* __restrict__ nodeF_A, ushort_t* __restrict__ gpack, int N)
{
    __shared__ __align__(16) bf16_t sx[64 * LD];
    const int n0 = blockIdx.x * 64;
    const int t = threadIdx.x;
    for (int i = t; i < 64 * 24; i += 256) {
        int r = i / 24, c4 = i % 24;
        int n = n0 + r;
        float4 v = (n < N) ? ((const float4*)h)[(size_t)n * 24 + c4]
                           : make_float4(0.f, 0.f, 0.f, 0.f);
        bf16_t* p = &sx[r * LD + c4 * 4];
        p[0] = (bf16_t)v.x; p[1] = (bf16_t)v.y; p[2] = (bf16_t)v.z; p[3] = (bf16_t)v.w;
    }
    __syncthreads();

    const int w = t >> 6, l = t & 63;
    const int lr = l & 15, lkb = (l >> 4) * 8;
    bf16x8 a[3];
    const bf16_t* aP = &sx[(w * 16 + lr) * LD + lkb];
#pragma unroll
    for (int kk = 0; kk < 3; ++kk) a[kk] = *(const bf16x8*)(aP + kk * 32);
    const int rowb = (l >> 4) * 4;

#pragma unroll
    for (int mat = 0; mat < 4; ++mat) {
        const int widx = (mat < 2) ? mat : mat + 1;
        const float* bias = (mat == 0) ? Ab : (mat == 1) ? Bb : (mat == 2) ? Db : Eb;
        f32x4 acc[6];
#pragma unroll
        for (int i = 0; i < 6; ++i) acc[i] = (f32x4){0.f, 0.f, 0.f, 0.f};
        const bf16x8* wp = (const bf16x8*)(wpA + (size_t)widx * 9216);
#pragma unroll
        for (int kk = 0; kk < 3; ++kk) {
#pragma unroll
            for (int tn = 0; tn < 6; ++tn) {
                bf16x8 b = wp[(tn * 3 + kk) * 64 + l];
                acc[tn] = __builtin_amdgcn_mfma_f32_16x16x32_bf16(a[kk], b, acc[tn], 0, 0, 0);
            }
        }
        float b6[6];
        {
            float2 b0 = *(const float2*)(bias + lr * 6);
            float2 b1 = *(const float2*)(bias + lr * 6 + 2);
            float2 b2 = *(const float2*)(bias + lr * 6 + 4);
            b6[0] = b0.x; b6[1] = b0.y; b6[2] = b1.x; b6[3] = b1.y; b6[4] = b2.x; b6[5] = b2.y;
        }
        if (mat == 3) {
            float2 c0 = *(const float2*)(Cb + lr * 6);
            float2 c1 = *(const float2*)(Cb + lr * 6 + 2);
            float2 c2 = *(const float2*)(Cb + lr * 6 + 4);
            b6[0] += c0.x; b6[1] += c0.y; b6[2] += c1.x; b6[3] += c1.y; b6[4] += c2.x; b6[5] += c2.y;
        }
#pragma unroll
        for (int i = 0; i < 4; ++i) {
            int n = n0 + w * 16 + rowb + i;
            if (n < N) {
                float v0 = acc[0][i] + b6[0], v1 = acc[1][i] + b6[1];
                float v2 = acc[2][i] + b6[2], v3 = acc[3][i] + b6[3];
                float v4 = acc[4][i] + b6[4], v5 = acc[5][i] + b6[5];
                if (mat == 0) {
                    float* p = nodeF_A + (size_t)n * 96 + lr * 6;
                    *(float2*)p = make_float2(v0, v1);
                    *(float2*)(p + 2) = make_float2(v2, v3);
                    *(float2*)(p + 4) = make_float2(v4, v5);
                } else {
                    size_t off = (mat == 1) ? ((size_t)n * 288 + lr * 12)
                               : (mat == 2) ? ((size_t)n * 288 + lr * 12 + 6)
                                            : ((size_t)n * 288 + 192 + lr * 6);
                    unsigned* op = (unsigned*)(gpack + off);
                    op[0] = pk2(v0, v1); op[1] = pk2(v2, v3); op[2] = pk2(v4, v5);
                }
            }
        }
    }
}

// ---------------- Ce GEMM: en_s[inv[row]][96] = bf16(e[row] @ Cw^T) ----------------
__global__ __launch_bounds__(256) void ce_gemm_kernel(
    const float* __restrict__ eP, const bf16_t* __restrict__ wpackC,
    const int* __restrict__ inv, ushort_t* __restrict__ en_s, int E)
{
    __shared__ __align__(16) bf16_t sx[64 * LD];
    const int n0 = blockIdx.x * 64;
    const int t = threadIdx.x;
    for (int i = t; i < 64 * 24; i += 256) {
        int r = i / 24, c4 = i % 24;
        int n = n0 + r;
        float4 v = (n < E) ? ((const float4*)eP)[(size_t)n * 24 + c4]
                           : make_float4(0.f, 0.f, 0.f, 0.f);
        bf16_t* p = &sx[r * LD + c4 * 4];
        p[0] = (bf16_t)v.x; p[1] = (bf16_t)v.y; p[2] = (bf16_t)v.z; p[3] = (bf16_t)v.w;
    }
    __syncthreads();

    const int w = t >> 6, l = t & 63;
    const int lr = l & 15, lkb = (l >> 4) * 8;
    f32x4 acc[6];
#pragma unroll
    for (int i = 0; i < 6; ++i) acc[i] = (f32x4){0.f, 0.f, 0.f, 0.f};
    const bf16_t* aP = &sx[(w * 16 + lr) * LD + lkb];
    const bf16x8* wp = (const bf16x8*)wpackC;
#pragma unroll
    for (int kk = 0; kk < 3; ++kk) {
        bf16x8 a = *(const bf16x8*)(aP + kk * 32);
#pragma unroll
        for (int tn = 0; tn < 6; ++tn) {
            bf16x8 b = wp[(tn * 3 + kk) * 64 + l];
            acc[tn] = __builtin_amdgcn_mfma_f32_16x16x32_bf16(a, b, acc[tn], 0, 0, 0);
        }
    }
    const int rowb = (l >> 4) * 4;
#pragma unroll
    for (int i = 0; i < 4; ++i) {
        int n = n0 + w * 16 + rowb + i;
        if (n < E) {
            int g = inv[n];
            unsigned* op = (unsigned*)(en_s + (size_t)g * 96 + lr * 6);
            op[0] = pk2(acc[0][i], acc[1][i]);
            op[1] = pk2(acc[2][i], acc[3][i]);
            op[2] = pk2(acc[4][i], acc[5][i]);
        }
    }
}

// ---------------- counting sort by dst ----------------
__global__ void hist_kernel(const int* __restrict__ dst, int* __restrict__ cnt, int E) {
    int i = blockIdx.x * 256 + threadIdx.x;
    if (i < E) atomicAdd(&cnt[dst[i]], 1);
}

// parallel unordered-base scan
__global__ __launch_bounds__(1024) void scan_assign_kernel(
    const int* __restrict__ cnt, int* __restrict__ startA, int* __restrict__ cursor,
    int* __restrict__ gtot, int N)
{
    __shared__ int wsum[16];
    __shared__ int sbase;
    const int t = threadIdx.x, w = t >> 6, l = t & 63;
    const int base = blockIdx.x * 1024;
    int v = (base + t < N) ? cnt[base + t] : 0;
    int x = v;
#pragma unroll
    for (int d = 1; d < 64; d <<= 1) {
        int y = __shfl_up(x, d, 64);
        if (l >= d) x += y;
    }
    if (l == 63) wsum[w] = x;
    __syncthreads();
    if (t == 0) {
        int run = 0;
#pragma unroll
        for (int i = 0; i < 16; ++i) { int tmp = wsum[i]; wsum[i] = run; run += tmp; }
        sbase = atomicAdd(gtot, run);
    }
    __syncthreads();
    int excl = sbase + wsum[w] + (x - v);
    if (base + t < N) { startA[base + t] = excl; cursor[base + t] = excl; }
}

// writes inv (orig->slot) and slot-order srcs; cursor ends at startA+cnt
__global__ void scatter_kernel(const int* __restrict__ dst, const int* __restrict__ src,
                               int* __restrict__ cursor, int* __restrict__ inv,
                               int* __restrict__ srcs, int E) {
    int i = blockIdx.x * 256 + threadIdx.x;
    if (i < E) {
        int d = dst[i];
        int p = atomicAdd(&cursor[d], 1);
        inv[i] = p;
        srcs[p] = src[i];
    }
}

// ---------------- CSR node-parallel aggregation ----------------
// 16-lane group per node; lane owns cols lr*6..lr*6+5.
// en_s (slot order): Ce in, e_new out (in place). Bh|Dh interleaved gather (one
// 24B span per edge per lane). h_new = Ah + sh/(sg+eps); BN stats; LWO flush.
__global__ __launch_bounds__(256, 8) void csr_agg_kernel(
    const int* __restrict__ startA, const int* __restrict__ rowend,
    const int* __restrict__ srcs,
    const ushort_t* __restrict__ gpack, ushort_t* __restrict__ en_s,
    const float* __restrict__ nodeF_A, float* __restrict__ h_new,
    float* __restrict__ stats, int N)
{
    __shared__ float bns[96], bnq[96], bsh[96], bqh[96];
    __shared__ int scnt;
    const int t = threadIdx.x;
    if (t == 0) scnt = 0;
    if (t < 96) { bns[t] = 0.f; bnq[t] = 0.f; bsh[t] = 0.f; bqh[t] = 0.f; }
    __syncthreads();

    const int gi = t >> 4, lr = t & 15, l = t & 63;
    const int n = blockIdx.x * 16 + gi;
    float ls[6] = {0, 0, 0, 0, 0, 0}, lq[6] = {0, 0, 0, 0, 0, 0};

    if (n < N) {
        const int beg = startA[n];
        const int end = rowend[n];
        float eh6[6];
        LD6(gpack + (size_t)n * 288 + 192 + lr * 6, eh6);
        float ash[6] = {0, 0, 0, 0, 0, 0}, asg[6] = {0, 0, 0, 0, 0, 0};
        for (int g = beg; g < end; ++g) {
            int s0 = srcs[g];
            float ce6[6], bh6[6], dh6[6], en6[6];
            LD6(en_s + (size_t)g * 96 + lr * 6, ce6);
            LD12(gpack + (size_t)s0 * 288 + lr * 12, bh6, dh6);
#pragma unroll
            for (int k = 0; k < 6; ++k) {
                float en = ce6[k] + dh6[k] + eh6[k];
                float sg = 1.f / (1.f + __expf(-en));
                ash[k] += sg * bh6[k]; asg[k] += sg;
                ls[k] += en; lq[k] += en * en;
                en6[k] = en;
            }
            unsigned* op = (unsigned*)(en_s + (size_t)g * 96 + lr * 6);
            op[0] = pk2(en6[0], en6[1]); op[1] = pk2(en6[2], en6[3]); op[2] = pk2(en6[4], en6[5]);
        }
        const float* ap = nodeF_A + (size_t)n * 96 + lr * 6;
        float* hp = h_new + (size_t)n * 96 + lr * 6;
#pragma unroll
        for (int k = 0; k < 6; ++k) {
            float v = ap[k] + ash[k] / (asg[k] + 1e-6f);
            hp[k] = v;
            atomicAdd(&bsh[lr * 6 + k], v);
            atomicAdd(&bqh[lr * 6 + k], v * v);
        }
    }
#pragma unroll
    for (int k = 0; k < 6; ++k) {
        float s = ls[k], q = lq[k];
        s += __shfl_xor(s, 16, 64); q += __shfl_xor(q, 16, 64);
        s += __shfl_xor(s, 32, 64); q += __shfl_xor(q, 32, 64);
        if (l < 16) {
            atomicAdd(&bns[lr * 6 + k], s);
            atomicAdd(&bnq[lr * 6 + k], q);
        }
    }
    __threadfence_block();
    int old = 0;
    if (l == 0) old = atomicAdd(&scnt, 1);
    old = __shfl(old, 0, 64);
    if (old == 3) {
        for (int j = l; j < 96; j += 64) {
            unsafeAtomicAdd(&stats[j], bsh[j]);
            unsafeAtomicAdd(&stats[96 + j], bqh[j]);
            unsafeAtomicAdd(&stats[192 + j], bns[j]);
            unsafeAtomicAdd(&stats[288 + j], bnq[j]);
        }
    }
}

// ---------------- edge output: natural order, gather e_new via inv ----------------
__global__ __launch_bounds__(256) void edge_out_b_kernel(
    const float* __restrict__ eP, const ushort_t* __restrict__ en_s,
    const int* __restrict__ inv, const float* __restrict__ coef,
    float* __restrict__ eout, long long total4)
{
    long long idx = (long long)blockIdx.x * 256 + threadIdx.x;
    if (idx >= total4) return;
    int row = (int)(idx / 24);
    int c4 = (int)(idx % 24) * 4;
    float4 res = ((const float4*)eP)[idx];
    int g = inv[row];
    ushort4 nb = *(const ushort4*)(en_s + (size_t)g * 96 + c4);
    float4 o;
    o.x = res.x + fmaxf(0.f, bf2f(nb.x) * coef[192 + c4 + 0] + coef[288 + c4 + 0]);
    o.y = res.y + fmaxf(0.f, bf2f(nb.y) * coef[192 + c4 + 1] + coef[288 + c4 + 1]);
    o.z = res.z + fmaxf(0.f, bf2f(nb.z) * coef[192 + c4 + 2] + coef[288 + c4 + 2]);
    o.w = res.w + fmaxf(0.f, bf2f(nb.w) * coef[192 + c4 + 3] + coef[288 + c4 + 3]);
    ((float4*)eout)[idx] = o;
}

// ---------------- stats -> scale/shift coefs ----------------
__global__ void finalize_stats_kernel(const float* __restrict__ stats, float* __restrict__ coef,
                                      const float* __restrict__ gh, const float* __restrict__ bh,
                                      const float* __restrict__ ge, const float* __restrict__ be,
                                      int N, int E)
{
    int t = threadIdx.x;
    if (t < 96) {
        float m = stats[t] / (float)N;
        float v = stats[96 + t] / (float)N - m * m;
        float rs = rsqrtf(v + 1e-5f);
        float sc = gh[t] * rs;
        coef[t] = sc;
        coef[96 + t] = bh[t] - m * sc;
    } else if (t < 192) {
        int c = t - 96;
        float m = stats[192 + c] / (float)E;
        float v = stats[288 + c] / (float)E - m * m;
        float rs = rsqrtf(v + 1e-5f);
        float sc = ge[c] * rs;
        coef[192 + c] = sc;
        coef[288 + c] = be[c] - m * sc;
    }
}

// ---------------- h output ----------------
__global__ __launch_bounds__(256) void h_out_kernel(
    const float* __restrict__ h, const float* __restrict__ h_new,
    const float* __restrict__ coef, float* __restrict__ out, int N)
{
    int idx = blockIdx.x * 256 + threadIdx.x;
    int total = N * 24;
    if (idx >= total) return;
    int c4 = (idx % 24) * 4;
    float4 hv = ((const float4*)h)[idx];
    float4 nv = ((const float4*)h_new)[idx];
    float4 o;
    o.x = hv.x + fmaxf(0.f, nv.x * coef[c4 + 0] + coef[96 + c4 + 0]);
    o.y = hv.y + fmaxf(0.f, nv.y * coef[c4 + 1] + coef[96 + c4 + 1]);
    o.z = hv.z + fmaxf(0.f, nv.z * coef[c4 + 2] + coef[96 + c4 + 2]);
    o.w = hv.w + fmaxf(0.f, nv.w * coef[c4 + 3] + coef[96 + c4 + 3]);
    ((float4*)out)[idx] = o;
}

extern "C" void kernel_launch(void* const* d_in, const int* in_sizes, int n_in,
                              void* d_out, int out_size, void* d_ws, size_t ws_size,
                              hipStream_t stream)
{
    const float* h   = (const float*)d_in[0];
    const float* e   = (const float*)d_in[1];
    const int*   src = (const int*)d_in[2];
    const int*   dst = (const int*)d_in[3];
    const float* Aw  = (const float*)d_in[4];
    const float* Ab  = (const float*)d_in[5];
    const float* Bw  = (const float*)d_in[6];
    const float* Bb  = (const float*)d_in[7];
    const float* Cw  = (const float*)d_in[8];
    const float* Cb  = (const float*)d_in[9];
    const float* Dw  = (const float*)d_in[10];
    const float* Db  = (const float*)d_in[11];
    const float* Ewt = (const float*)d_in[12];
    const float* Eb  = (const float*)d_in[13];
    const float* gh  = (const float*)d_in[14];
    const float* bh  = (const float*)d_in[15];
    const float* ge  = (const float*)d_in[16];
    const float* be  = (const float*)d_in[17];

    const int N = in_sizes[0] / 96;
    const int E = in_sizes[2];

    float* ws        = (float*)d_ws;
    float* nodeF_A   = ws;                               // N*96 f32
    float* h_new     = nodeF_A + (size_t)N * 96;         // N*96 f32
    float* stats     = h_new + (size_t)N * 96;           // 384
    float* coef      = stats + 384;                      // 384
    bf16_t* wpA      = (bf16_t*)(coef + 384);            // 5*9216 bf16
    int* cnt         = (int*)(wpA + 5 * 9216);           // N
    int* startA      = cnt + N;                          // N
    int* cursor      = startA + N;                       // N
    int* srcs        = cursor + N;                       // E
    int* inv         = srcs + E;                         // E
    ushort_t* gpack  = (ushort_t*)(inv + E);             // N*288
    ushort_t* en_s   = gpack + (size_t)N * 288;          // E*96
    int* gtot        = (int*)(en_s + (size_t)E * 96);    // 1

    const int nblk64 = (E + 63) / 64;
    const int nscan = (N + 1023) / 1024;

    hipMemsetAsync(cnt, 0, (size_t)N * sizeof(int), stream);
    hipMemsetAsync(gtot, 0, sizeof(int), stream);
    hipMemsetAsync(stats, 0, 384 * sizeof(float), stream);

    pack_all_kernel<<<dim3(23), dim3(256), 0, stream>>>(Aw, Bw, Cw, Dw, Ewt, wpA);
    node_gemm_all_kernel<<<dim3((N + 63) / 64), dim3(256), 0, stream>>>(
        h, wpA, Ab, Bb, Db, Eb, Cb, nodeF_A, gpack, N);
    hist_kernel<<<dim3((E + 255) / 256), dim3(256), 0, stream>>>(dst, cnt, E);
    scan_assign_kernel<<<dim3(nscan), dim3(1024), 0, stream>>>(cnt, startA, cursor, gtot, N);
    scatter_kernel<<<dim3((E + 255) / 256), dim3(256), 0, stream>>>(
        dst, src, cursor, inv, srcs, E);
    ce_gemm_kernel<<<dim3(nblk64), dim3(256), 0, stream>>>(
        e, wpA + 2 * 9216, inv, en_s, E);

    // cursor now holds row ends (startA + cnt)
    csr_agg_kernel<<<dim3((N + 15) / 16), dim3(256), 0, stream>>>(
        startA, cursor, srcs, gpack, en_s, nodeF_A, h_new, stats, N);

    finalize_stats_kernel<<<dim3(1), dim3(192), 0, stream>>>(stats, coef, gh, bh, ge, be, N, E);
    h_out_kernel<<<dim3((N * 24 + 255) / 256), dim3(256), 0, stream>>>(
        h, h_new, coef, (float*)d_out, N);

    long long total4 = (long long)E * 24;
    edge_out_b_kernel<<<dim3((unsigned)((total4 + 255) / 256)), dim3(256), 0, stream>>>(
        e, en_s, inv, coef, (float*)d_out + (size_t)N * 96, total4);
}